// Round 12
// baseline (51703.931 us; speedup 1.0000x reference)
//
#include <hip/hip_runtime.h>
#include <hip/hip_bf16.h>

// Problem constants
constexpr int kN = 8192;
constexpr int kF = 256;
constexpr int kH = 512;
constexpr int kL = 512;
constexpr int kE = kN * 4;           // 32768 edges

using ull = unsigned long long;
typedef unsigned int u32x4 __attribute__((ext_vector_type(4)));

__device__ __forceinline__ float sigm(float x) { return 1.f / (1.f + __expf(-x)); }

__device__ __forceinline__ float4 ld_bf4(const __hip_bfloat16* p) {
    uint2 u = *(const uint2*)p;
    float4 r;
    r.x = __uint_as_float(u.x << 16);
    r.y = __uint_as_float(u.x & 0xffff0000u);
    r.z = __uint_as_float(u.y << 16);
    r.w = __uint_as_float(u.y & 0xffff0000u);
    return r;
}

// stamped 8-byte pair: low dword = float bits, high dword = stamp (step+1).
// uni==true : verified same-XCD -> PLAIN store (write-through L1 into the XCD
//             L2, the intra-XCD coherence point; fast ack, no MALL).
// uni==false: agent-scope (sc1/MALL) store, any placement.
__device__ __forceinline__ void st_pair(ull* p, float v, unsigned stamp, bool uni) {
    ull u = ((ull)stamp << 32) | (ull)__float_as_uint(v);
    if (uni) __hip_atomic_store(p, u, __ATOMIC_RELAXED, __HIP_MEMORY_SCOPE_WORKGROUP);
    else     __hip_atomic_store(p, u, __ATOMIC_RELAXED, __HIP_MEMORY_SCOPE_AGENT);
}
__device__ __forceinline__ ull ld_raw(const ull* p) {
    return __hip_atomic_load(p, __ATOMIC_RELAXED, __HIP_MEMORY_SCOPE_AGENT);
}

// ---------------------------------------------------------------------------
__global__ void k_init(float* __restrict__ out, const float* __restrict__ bdo,
                       ull* __restrict__ hpay, ull* __restrict__ zpay,
                       int* __restrict__ claims, int* __restrict__ xcc_tab) {
    int idx = blockIdx.x * 256 + threadIdx.x;
    if (idx < kE) out[idx] = bdo[0];
    if (idx < 4 * 512 * 4) hpay[idx] = 0ull;          // [r][k][d]
    if (idx < 4 * 256 * 32) zpay[idx] = 0ull;         // [r][tid][b]
    if (idx < 2) claims[idx] = 0;
    if (idx < 64) xcc_tab[idx] = 0;
}

__global__ void k_zero(float* __restrict__ out) {
    int idx = blockIdx.x * 256 + threadIdx.x;
    if (idx < kE) out[idx] = 0.f;
}

// ---------------------------------------------------------------------------
// Recurrent kernel: round-5 geometry (32 blocks/dir x 256 thr, XCD-claimed +
// placement VERIFIED). Exchange layouts are consumer-contiguous:
//   zpay[r][tid][b]  (thread's 32 partials = 256 B contiguous)
//   hpay[r][k][d]    (thread's 8 pairs (k=2t,2t+1; d=0..3) = 64 B contiguous)
// uni path: plain stores (L2 write-back) + ONE asm batch of 20
// global_load_dwordx4 sc0 (L1-bypass, L2-read) + single vmcnt(0) per sweep.
// !uni path: agent atomics (round-11 logic, proven 45.6 ms).
// ---------------------------------------------------------------------------
__global__ __launch_bounds__(256, 1) void k_recur(
    const float* __restrict__ edges,
    const float* __restrict__ Wih_f, const float* __restrict__ Whh_f, const float* __restrict__ b_f,
    const float* __restrict__ Wih_b, const float* __restrict__ Whh_b, const float* __restrict__ b_b,
    const float* __restrict__ Wa, const float* __restrict__ ba,
    const float* __restrict__ Wao, const float* __restrict__ bao,
    __hip_bfloat16* __restrict__ arc_f, __hip_bfloat16* __restrict__ arc_b,
    ull* __restrict__ hpay, ull* __restrict__ zpay,
    int* __restrict__ claims, int* __restrict__ xcc_tab) {

    // ---- XCD-affine slot claim + placement verification ----
    __shared__ int s_slot, s_uni;
    if (threadIdx.x == 0) {
        unsigned xcc = (unsigned)__builtin_amdgcn_s_getreg((31 << 11) | (0 << 6) | 20) & 15u;
        int slot = -1;
        if (xcc <= 1) {
            int c = atomicAdd(&claims[xcc], 1);
            if (c < 32) slot = (int)xcc * 32 + c;
        } else {
            for (int sl = 0; sl < 64; sl++) __builtin_amdgcn_s_sleep(64);
            for (int dd = 0; dd < 2 && slot < 0; dd++) {
                if (__hip_atomic_load(&claims[dd], __ATOMIC_RELAXED,
                                      __HIP_MEMORY_SCOPE_AGENT) < 32) {
                    int c = atomicAdd(&claims[dd], 1);
                    if (c < 32) slot = dd * 32 + c;
                }
            }
        }
        s_slot = slot;
        if (slot >= 0) {
            __hip_atomic_store(&xcc_tab[slot], 0x100 | (int)xcc,
                               __ATOMIC_RELAXED, __HIP_MEMORY_SCOPE_AGENT);
            const int base = (slot >> 5) * 32;
            int u2 = 1;
            for (int k2 = 0; k2 < 32; k2++) {
                int v;
                do { v = __hip_atomic_load(&xcc_tab[base + k2], __ATOMIC_RELAXED,
                                           __HIP_MEMORY_SCOPE_AGENT); } while (!(v & 0x100));
                u2 &= ((v & 0xff) == (int)xcc) ? 1 : 0;
            }
            s_uni = u2;
        }
    }
    __syncthreads();
    const int slot = s_slot;
    if (slot < 0) return;
    const bool uni = (s_uni != 0);
    const int dir = slot >> 5;
    const int b   = slot & 31;

    const float* __restrict__ Whh = dir ? Whh_b : Whh_f;
    const float* __restrict__ Wih = dir ? Wih_b : Wih_f;
    const float* __restrict__ bia = dir ? b_b  : b_f;
    __hip_bfloat16* __restrict__ arc = dir ? arc_b : arc_f;
    const int tid = threadIdx.x;

    // matvec roles: 64 gate rows x 4-way K split
    const int jl = tid >> 2, ks = tid & 3;
    const int Jg = (jl >> 4) * kH + b * 16 + (jl & 15);
    // gate / xproj / z roles: wave = arc, lane = gate row (or attention unit)
    const int d_g = tid >> 6, jl2 = tid & 63;
    const int Jg2 = (jl2 >> 4) * kH + b * 16 + (jl2 & 15);
    const int a_id = jl2;

    float w[128];
    {
        const float* wr = Whh + (size_t)Jg * kH + ks * 128;
        #pragma unroll
        for (int kk = 0; kk < 128; kk++) w[kk] = wr[kk];
    }
    float wih[64];
    {
        const float* wr = Wih + (size_t)Jg2 * kF + d_g * 64;
        #pragma unroll
        for (int kk = 0; kk < 64; kk++) wih[kk] = wr[kk];
    }
    const float biasR = bia[Jg2];
    const float baR   = ba[a_id];
    const float WaoR  = Wao[a_id];
    const float baoR  = bao[0];
    const float wax0  = Wa[(size_t)a_id * 515 + 512];
    const float wax1  = Wa[(size_t)a_id * 515 + 513];
    const float wax2  = Wa[(size_t)a_id * 515 + 514];

    __shared__ __align__(16) float hprev_p[4 * 132];
    __shared__ float Mh[4][64];
    __shared__ float cring[4][16];
    __shared__ float gl[4][64];
    __shared__ float harcl[4][16];
    __shared__ float carcl[4][16];
    __shared__ float logit_l[4];
    __shared__ float WaS[64][17];
    __shared__ __align__(16) float x_s[4][256];
    __shared__ float xpart[4][4][64];

    for (int l2 = tid; l2 < 4 * 132; l2 += 256) hprev_p[l2] = 0.f;
    Mh[tid >> 6][tid & 63] = 0.f;
    if (tid < 64) cring[tid >> 4][tid & 15] = 0.f;
    for (int l2 = tid; l2 < 1024; l2 += 256)
        WaS[l2 >> 4][l2 & 15] = Wa[(size_t)(l2 >> 4) * 515 + b * 16 + (l2 & 15)];
    __syncthreads();

#define XLOAD(nn, XV) do {                                                    \
        int row_;                                                             \
        if (dir == 0) row_ = (nn) * 4 + d_g;                                  \
        else { row_ = ((nn) + 1 + d_g) * 4 + d_g;                             \
               if (row_ > kE - 1) row_ = kE - 1; }                            \
        XV = *(const float4*)(edges + (size_t)row_ * kF + 4 * jl2);           \
    } while (0)

#define XFIN(XV, XPOUT, ZXOUT) do {                                           \
        *(float4*)(&x_s[d_g][4 * jl2]) = XV;                                  \
        __syncthreads();                                                      \
        float p0_ = 0.f, p1_ = 0.f, p2_ = 0.f, p3_ = 0.f;                     \
        _Pragma("unroll")                                                     \
        for (int k4_ = 0; k4_ < 16; k4_++) {                                  \
            float4 a0_ = *(const float4*)&x_s[0][d_g * 64 + k4_ * 4];         \
            float4 a1_ = *(const float4*)&x_s[1][d_g * 64 + k4_ * 4];         \
            float4 a2_ = *(const float4*)&x_s[2][d_g * 64 + k4_ * 4];         \
            float4 a3_ = *(const float4*)&x_s[3][d_g * 64 + k4_ * 4];         \
            float w0_ = wih[k4_*4], w1_ = wih[k4_*4+1];                       \
            float w2_ = wih[k4_*4+2], w3_ = wih[k4_*4+3];                     \
            p0_ += w0_*a0_.x + w1_*a0_.y + w2_*a0_.z + w3_*a0_.w;             \
            p1_ += w0_*a1_.x + w1_*a1_.y + w2_*a1_.z + w3_*a1_.w;             \
            p2_ += w0_*a2_.x + w1_*a2_.y + w2_*a2_.z + w3_*a2_.w;             \
            p3_ += w0_*a3_.x + w1_*a3_.y + w2_*a3_.z + w3_*a3_.w;             \
        }                                                                     \
        xpart[d_g][0][jl2] = p0_; xpart[d_g][1][jl2] = p1_;                   \
        xpart[d_g][2][jl2] = p2_; xpart[d_g][3][jl2] = p3_;                   \
        __syncthreads();                                                      \
        XPOUT = biasR + xpart[0][d_g][jl2] + xpart[1][d_g][jl2]               \
                      + xpart[2][d_g][jl2] + xpart[3][d_g][jl2];              \
        ZXOUT = baR + wax0 * x_s[d_g][0] + wax1 * x_s[d_g][1]                 \
                    + wax2 * x_s[d_g][2];                                     \
    } while (0)

    const int i0 = dir ? kN - 1 : 0;
    float xp, zxv;
    {
        float4 xv0;
        XLOAD(i0, xv0);
        XFIN(xv0, xp, zxv);
    }

    for (int t = 0; t < kN; t++) {
        const int i = dir ? kN - 1 - t : t;
        const unsigned stamp = (unsigned)(t + 1);
        const int par = t & 1;
        const int r = dir * 2 + par;

        // ---- prefetch next step's edge row ----
        float4 xv_n;
        {
            const int nn = (t + 1 < kN) ? (dir ? i - 1 : i + 1) : i;
            XLOAD(nn, xv_n);
        }

        // ---- A: M[iprev] = hprev . Whh^T (own 64 rows) ----
        float acc = 0.f;
        {
            const float* hp = &hprev_p[ks * 132];
            #pragma unroll
            for (int kk = 0; kk < 128; kk += 4) {
                float4 hv = *(const float4*)(hp + kk);
                acc += w[kk] * hv.x + w[kk+1] * hv.y + w[kk+2] * hv.z + w[kk+3] * hv.w;
            }
        }
        acc += __shfl_xor(acc, 1);
        acc += __shfl_xor(acc, 2);
        const int iprev = dir ? i + 1 : i - 1;
        if (ks == 0) Mh[iprev & 3][jl] = acc;
        __syncthreads();

        // ---- B: gates ----
        {
            const int p = dir ? i + 1 + d_g : i - 1 - d_g;
            gl[d_g][jl2] = xp + Mh[p & 3][jl2];
        }
        __syncthreads();
        if (tid < 64) {
            const int d3 = tid >> 4, s3 = tid & 15;
            const int pp = dir ? i + 1 + d3 : i - 1 - d3;
            const bool v3 = dir ? (pp < kN) : (pp >= 0);
            float gi = gl[d3][s3],      gf = gl[d3][16 + s3];
            float gg = gl[d3][32 + s3], go = gl[d3][48 + s3];
            float cp = cring[pp & 3][s3];
            float c = sigm(gf) * cp + sigm(gi) * tanhf(gg);
            float h = sigm(go) * tanhf(c);
            float hm = v3 ? h : 0.f, cm = v3 ? c : 0.f;
            harcl[d3][s3] = hm; carcl[d3][s3] = cm;
            arc[((size_t)i * 4 + d3) * kH + b * 16 + s3] = __float2bfloat16(hm);
            // hpay[r][k][d], k = b*16+s3
            st_pair(hpay + ((size_t)r * 512 + b * 16 + s3) * 4 + d3, hm, stamp, uni);
        }
        __syncthreads();
        // z partial over own 16 h-dims -> zpay[r][tid][b]
        {
            float zp = 0.f;
            #pragma unroll
            for (int ss = 0; ss < 16; ss++) zp += WaS[a_id][ss] * harcl[d_g][ss];
            st_pair(zpay + ((size_t)(r * 256) + tid) * 32 + b, zp, stamp, uni);
        }

        // ---- C: next step's input projection (overlaps publish visibility) ----
        float xp_n, zx_n;
        XFIN(xv_n, xp_n, zx_n);

        // ---- E: resolve z + h ----
        const ull* zb2 = zpay + ((size_t)(r * 256) + tid) * 32;       // 32 pairs, 256 B
        const ull* hb2 = hpay + ((size_t)r * 512 + 2 * tid) * 4;      // 8 pairs, 64 B
        float zsum = 0.f;
        float hval[8];

        if (uni) {
            u32x4 q0,q1,q2,q3,q4,q5,q6,q7,q8,q9,q10,q11,q12,q13,q14,q15,hA,hB,hC,hD;
            int guard = 0;
            for (;;) {
                asm volatile(
                    "global_load_dwordx4 %0, %20, off sc0\n\t"
                    "global_load_dwordx4 %1, %20, off offset:16 sc0\n\t"
                    "global_load_dwordx4 %2, %20, off offset:32 sc0\n\t"
                    "global_load_dwordx4 %3, %20, off offset:48 sc0\n\t"
                    "global_load_dwordx4 %4, %20, off offset:64 sc0\n\t"
                    "global_load_dwordx4 %5, %20, off offset:80 sc0\n\t"
                    "global_load_dwordx4 %6, %20, off offset:96 sc0\n\t"
                    "global_load_dwordx4 %7, %20, off offset:112 sc0\n\t"
                    "global_load_dwordx4 %8, %20, off offset:128 sc0\n\t"
                    "global_load_dwordx4 %9, %20, off offset:144 sc0\n\t"
                    "global_load_dwordx4 %10, %20, off offset:160 sc0\n\t"
                    "global_load_dwordx4 %11, %20, off offset:176 sc0\n\t"
                    "global_load_dwordx4 %12, %20, off offset:192 sc0\n\t"
                    "global_load_dwordx4 %13, %20, off offset:208 sc0\n\t"
                    "global_load_dwordx4 %14, %20, off offset:224 sc0\n\t"
                    "global_load_dwordx4 %15, %20, off offset:240 sc0\n\t"
                    "global_load_dwordx4 %16, %21, off sc0\n\t"
                    "global_load_dwordx4 %17, %21, off offset:16 sc0\n\t"
                    "global_load_dwordx4 %18, %21, off offset:32 sc0\n\t"
                    "global_load_dwordx4 %19, %21, off offset:48 sc0\n\t"
                    "s_waitcnt vmcnt(0)"
                    : "=&v"(q0),"=&v"(q1),"=&v"(q2),"=&v"(q3),
                      "=&v"(q4),"=&v"(q5),"=&v"(q6),"=&v"(q7),
                      "=&v"(q8),"=&v"(q9),"=&v"(q10),"=&v"(q11),
                      "=&v"(q12),"=&v"(q13),"=&v"(q14),"=&v"(q15),
                      "=&v"(hA),"=&v"(hB),"=&v"(hC),"=&v"(hD)
                    : "v"(zb2), "v"(hb2)
                    : "memory");
                unsigned bad =
                    (q0.y^stamp)|(q0.w^stamp)|(q1.y^stamp)|(q1.w^stamp)|
                    (q2.y^stamp)|(q2.w^stamp)|(q3.y^stamp)|(q3.w^stamp)|
                    (q4.y^stamp)|(q4.w^stamp)|(q5.y^stamp)|(q5.w^stamp)|
                    (q6.y^stamp)|(q6.w^stamp)|(q7.y^stamp)|(q7.w^stamp)|
                    (q8.y^stamp)|(q8.w^stamp)|(q9.y^stamp)|(q9.w^stamp)|
                    (q10.y^stamp)|(q10.w^stamp)|(q11.y^stamp)|(q11.w^stamp)|
                    (q12.y^stamp)|(q12.w^stamp)|(q13.y^stamp)|(q13.w^stamp)|
                    (q14.y^stamp)|(q14.w^stamp)|(q15.y^stamp)|(q15.w^stamp)|
                    (hA.y^stamp)|(hA.w^stamp)|(hB.y^stamp)|(hB.w^stamp)|
                    (hC.y^stamp)|(hC.w^stamp)|(hD.y^stamp)|(hD.w^stamp);
                if (bad == 0u || ++guard > 1024) break;   // guard: fail-fast, no hang
            }
            zsum = __uint_as_float(q0.x)+__uint_as_float(q0.z)
                 + __uint_as_float(q1.x)+__uint_as_float(q1.z)
                 + __uint_as_float(q2.x)+__uint_as_float(q2.z)
                 + __uint_as_float(q3.x)+__uint_as_float(q3.z)
                 + __uint_as_float(q4.x)+__uint_as_float(q4.z)
                 + __uint_as_float(q5.x)+__uint_as_float(q5.z)
                 + __uint_as_float(q6.x)+__uint_as_float(q6.z)
                 + __uint_as_float(q7.x)+__uint_as_float(q7.z)
                 + __uint_as_float(q8.x)+__uint_as_float(q8.z)
                 + __uint_as_float(q9.x)+__uint_as_float(q9.z)
                 + __uint_as_float(q10.x)+__uint_as_float(q10.z)
                 + __uint_as_float(q11.x)+__uint_as_float(q11.z)
                 + __uint_as_float(q12.x)+__uint_as_float(q12.z)
                 + __uint_as_float(q13.x)+__uint_as_float(q13.z)
                 + __uint_as_float(q14.x)+__uint_as_float(q14.z)
                 + __uint_as_float(q15.x)+__uint_as_float(q15.z);
            hval[0] = __uint_as_float(hA.x); hval[1] = __uint_as_float(hA.z);
            hval[2] = __uint_as_float(hB.x); hval[3] = __uint_as_float(hB.z);
            hval[4] = __uint_as_float(hC.x); hval[5] = __uint_as_float(hC.z);
            hval[6] = __uint_as_float(hD.x); hval[7] = __uint_as_float(hD.z);
        } else {
            ull zv_[32];
            #pragma unroll
            for (int bb = 0; bb < 32; bb++) zv_[bb] = ld_raw(zb2 + bb);
            ull hv_[8];
            #pragma unroll
            for (int q = 0; q < 8; q++) hv_[q] = ld_raw(hb2 + q);
            for (;;) {
                bool ok = true;
                #pragma unroll
                for (int bb = 0; bb < 32; bb++)
                    ok &= ((unsigned)(zv_[bb] >> 32) == stamp);
                if (ok) break;
                __builtin_amdgcn_s_sleep(2);
                #pragma unroll
                for (int bb = 0; bb < 32; bb++)
                    if ((unsigned)(zv_[bb] >> 32) != stamp) zv_[bb] = ld_raw(zb2 + bb);
            }
            #pragma unroll
            for (int bb = 0; bb < 32; bb++) zsum += __uint_as_float((unsigned)zv_[bb]);
            for (;;) {
                bool ok = true;
                #pragma unroll
                for (int q = 0; q < 8; q++)
                    ok &= ((unsigned)(hv_[q] >> 32) == stamp);
                if (ok) break;
                __builtin_amdgcn_s_sleep(2);
                #pragma unroll
                for (int q = 0; q < 8; q++)
                    if ((unsigned)(hv_[q] >> 32) != stamp) hv_[q] = ld_raw(hb2 + q);
            }
            #pragma unroll
            for (int q = 0; q < 8; q++) hval[q] = __uint_as_float((unsigned)hv_[q]);
        }

        float zv = fmaxf(zsum + zxv, 0.f);
        float lv = WaoR * zv;
        #pragma unroll
        for (int o2 = 1; o2 < 64; o2 <<= 1) lv += __shfl_xor(lv, o2);
        if (a_id == 0) {
            const int pp = dir ? i + 1 + d_g : i - 1 - d_g;
            const bool v3 = dir ? (pp < kN) : (pp >= 0);
            logit_l[d_g] = v3 ? tanhf(lv + baoR) : -1e9f;
        }
        __syncthreads();

        float l0 = logit_l[0], l1 = logit_l[1], l2 = logit_l[2], l3 = logit_l[3];
        float mx = fmaxf(fmaxf(l0, l1), fmaxf(l2, l3));
        float e0 = __expf(l0 - mx), e1 = __expf(l1 - mx);
        float e2 = __expf(l2 - mx), e3 = __expf(l3 - mx);
        float inv = 1.f / (e0 + e1 + e2 + e3);
        float wg[4] = { e0 * inv, e1 * inv, e2 * inv, e3 * inv };

        // hval layout: [k=2tid: d0..d3][k=2tid+1: d0..d3]
        float hn0 = wg[0]*hval[0] + wg[1]*hval[1] + wg[2]*hval[2] + wg[3]*hval[3];
        float hn1 = wg[0]*hval[4] + wg[1]*hval[5] + wg[2]*hval[6] + wg[3]*hval[7];
        {
            const int g = 2 * tid;
            const int ch = g >> 7, wi = g & 127;
            hprev_p[ch * 132 + wi]     = hn0;
            hprev_p[ch * 132 + wi + 1] = hn1;
        }
        if (tid < 16) {
            float cn = wg[0] * carcl[0][tid] + wg[1] * carcl[1][tid]
                     + wg[2] * carcl[2][tid] + wg[3] * carcl[3][tid];
            cring[i & 3][tid] = cn;
        }
        __syncthreads();

        xp = xp_n; zxv = zx_n;
    }
#undef XLOAD
#undef XFIN
}

// ---------------------------------------------------------------------------
// decoder: out[e] += sum_l Wdo[l] * relu(bd[l] + sum_k Wd[l,k] feat[e,k])
// ---------------------------------------------------------------------------
__global__ __launch_bounds__(256) void k_dec(
    const __hip_bfloat16* __restrict__ arc_f, const __hip_bfloat16* __restrict__ arc_b,
    const float* __restrict__ Wd, const float* __restrict__ bd,
    const float* __restrict__ Wdo, float* __restrict__ out) {
    const int e0 = blockIdx.x * 128;
    const int l0 = blockIdx.y * 128;
    __shared__ __align__(16) float As[8][128];
    __shared__ __align__(16) float Bs[8][128];
    const int tid = threadIdx.x;
    const int tx = tid & 15, ty = tid >> 4;
    const int lr = tid & 127, kq = tid >> 7;

    const int e = e0 + lr;
    const int j = e >> 2, d = e & 3;
    const int jb = j - 1 - d;
    const __hip_bfloat16* frow  = arc_f + (size_t)e * kH;
    const __hip_bfloat16* brow2 = (jb >= 0) ? (arc_b + ((size_t)jb * 4 + d) * kH) : nullptr;
    const float* wrow = Wd + (size_t)(l0 + lr) * (2 * kH);

    float acc[8][8] = {};
    for (int k0 = 0; k0 < 2 * kH; k0 += 8) {
        const int kk = k0 + kq * 4;
        float4 av4;
        if (kk < kH) av4 = ld_bf4(frow + kk);
        else if (brow2) av4 = ld_bf4(brow2 + (kk - kH));
        else av4 = make_float4(0.f, 0.f, 0.f, 0.f);
        float4 bv4 = *(const float4*)(wrow + kk);
        __syncthreads();
        As[kq*4+0][lr] = av4.x; As[kq*4+1][lr] = av4.y;
        As[kq*4+2][lr] = av4.z; As[kq*4+3][lr] = av4.w;
        Bs[kq*4+0][lr] = bv4.x; Bs[kq*4+1][lr] = bv4.y;
        Bs[kq*4+2][lr] = bv4.z; Bs[kq*4+3][lr] = bv4.w;
        __syncthreads();
        #pragma unroll
        for (int kt = 0; kt < 8; kt++) {
            __align__(16) float a0[8], b0[8];
            *(float4*)&a0[0] = *(const float4*)&As[kt][ty*8];
            *(float4*)&a0[4] = *(const float4*)&As[kt][ty*8+4];
            *(float4*)&b0[0] = *(const float4*)&Bs[kt][tx*8];
            *(float4*)&b0[4] = *(const float4*)&Bs[kt][tx*8+4];
            #pragma unroll
            for (int mi = 0; mi < 8; mi++)
                #pragma unroll
                for (int ni = 0; ni < 8; ni++)
                    acc[mi][ni] += a0[mi] * b0[ni];
        }
    }
    #pragma unroll
    for (int mi = 0; mi < 8; mi++) {
        float sacc = 0.f;
        #pragma unroll
        for (int ni = 0; ni < 8; ni++) {
            int l = l0 + tx * 8 + ni;
            sacc += Wdo[l] * fmaxf(acc[mi][ni] + bd[l], 0.f);
        }
        sacc += __shfl_xor(sacc, 1);
        sacc += __shfl_xor(sacc, 2);
        sacc += __shfl_xor(sacc, 4);
        sacc += __shfl_xor(sacc, 8);
        if (tx == 0) atomicAdd(out + e0 + ty * 8 + mi, sacc);
    }
}

// ---------------------------------------------------------------------------
extern "C" void kernel_launch(void* const* d_in, const int* in_sizes, int n_in,
                              void* d_out, int out_size, void* d_ws, size_t ws_size,
                              hipStream_t stream) {
    const float* edges = (const float*)d_in[0];
    const float* Wih_f = (const float*)d_in[1];
    const float* Whh_f = (const float*)d_in[2];
    const float* b_f   = (const float*)d_in[3];
    const float* Wih_b = (const float*)d_in[4];
    const float* Whh_b = (const float*)d_in[5];
    const float* b_b   = (const float*)d_in[6];
    const float* Wa    = (const float*)d_in[7];
    const float* ba    = (const float*)d_in[8];
    const float* Wao   = (const float*)d_in[9];
    const float* bao   = (const float*)d_in[10];
    const float* Wd    = (const float*)d_in[11];
    const float* bd    = (const float*)d_in[12];
    const float* Wdo   = (const float*)d_in[13];
    const float* bdo   = (const float*)d_in[14];
    float* out = (float*)d_out;

    char* ws = (char*)d_ws;
    size_t off = 0;
    __hip_bfloat16* arc_f = (__hip_bfloat16*)(ws + off); off += (size_t)kE * kH * 2;  // 32 MB
    __hip_bfloat16* arc_b = (__hip_bfloat16*)(ws + off); off += (size_t)kE * kH * 2;  // 32 MB
    ull* hpay = (ull*)(ws + off); off += (size_t)4 * 512 * 4 * 8;                     // 64 KB
    ull* zpay = (ull*)(ws + off); off += (size_t)4 * 256 * 32 * 8;                    // 256 KB
    int* claims = (int*)(ws + off); off += 64;
    int* xcc_tab = (int*)(ws + off); off += 256;

    if (ws_size < off) {
        hipLaunchKernelGGL(k_zero, dim3((kE + 255) / 256), dim3(256), 0, stream, out);
        return;
    }

    hipLaunchKernelGGL(k_init, dim3(128), dim3(256), 0, stream,
                       out, bdo, hpay, zpay, claims, xcc_tab);
    hipLaunchKernelGGL(k_recur, dim3(512), dim3(256), 0, stream,
                       edges, Wih_f, Whh_f, b_f, Wih_b, Whh_b, b_b,
                       Wa, ba, Wao, bao, arc_f, arc_b, hpay, zpay, claims, xcc_tab);
    hipLaunchKernelGGL(k_dec, dim3(kE / 128, kL / 128), dim3(256), 0, stream,
                       arc_f, arc_b, Wd, bd, Wdo, out);
}

// Round 13
// 45465.915 us; speedup vs baseline: 1.1372x; 1.1372x over previous
//
#include <hip/hip_runtime.h>
#include <hip/hip_bf16.h>

// Problem constants
constexpr int kN = 8192;
constexpr int kF = 256;
constexpr int kH = 512;
constexpr int kL = 512;
constexpr int kE = kN * 4;           // 32768 edges

using ull = unsigned long long;

__device__ __forceinline__ float sigm(float x) { return 1.f / (1.f + __expf(-x)); }

__device__ __forceinline__ float4 ld_bf4(const __hip_bfloat16* p) {
    uint2 u = *(const uint2*)p;
    float4 r;
    r.x = __uint_as_float(u.x << 16);
    r.y = __uint_as_float(u.x & 0xffff0000u);
    r.z = __uint_as_float(u.y << 16);
    r.w = __uint_as_float(u.y & 0xffff0000u);
    return r;
}

// stamped 8-byte pair: low = float bits, high = stamp (step+1)
// relaxed agent-scope atomics: the only encoding that both pipelines and is
// safe (volatile -> serialized vmcnt(0) [r6]; L2/sc0 path [r12] proved the
// traffic moves to L2 but the time is invariant -> tier doesn't matter).
__device__ __forceinline__ void st_pair(ull* p, float v, unsigned stamp) {
    ull u = ((ull)stamp << 32) | (ull)__float_as_uint(v);
    __hip_atomic_store(p, u, __ATOMIC_RELAXED, __HIP_MEMORY_SCOPE_AGENT);
}
__device__ __forceinline__ ull ld_raw(const ull* p) {
    return __hip_atomic_load(p, __ATOMIC_RELAXED, __HIP_MEMORY_SCOPE_AGENT);
}

// ---------------------------------------------------------------------------
__global__ void k_init(float* __restrict__ out, const float* __restrict__ bdo,
                       ull* __restrict__ hpay, ull* __restrict__ zpay,
                       int* __restrict__ claims) {
    int idx = blockIdx.x * 256 + threadIdx.x;
    if (idx < kE) out[idx] = bdo[0];
    if (idx < 2 * 2 * 4 * kH) hpay[idx] = 0ull;
    if (idx < 2 * 2 * 32 * 256) zpay[idx] = 0ull;
    if (idx < 2) claims[idx] = 0;
}

__global__ void k_zero(float* __restrict__ out) {
    int idx = blockIdx.x * 256 + threadIdx.x;
    if (idx < kE) out[idx] = 0.f;
}

// ---------------------------------------------------------------------------
// Recurrent kernel: round-11 structure (best measured: 45.6 ms) with the
// gate/cell phases FUSED per-wave: cell reads parity-buffered xpl + Mh
// directly (no gl staging), z partial rides the intra-wave harcl dependency.
// 7 barriers/step -> 5; h/z published one barrier earlier.
// 512 candidate blocks; 32 working blocks/dir claimed by XCD.
// Block b owns h-dims [b*16,b*16+16) -> 64 gate rows (Whh slice in VGPRs).
// ---------------------------------------------------------------------------
__global__ __launch_bounds__(256, 1) void k_recur(
    const float* __restrict__ edges,
    const float* __restrict__ Wih_f, const float* __restrict__ Whh_f, const float* __restrict__ b_f,
    const float* __restrict__ Wih_b, const float* __restrict__ Whh_b, const float* __restrict__ b_b,
    const float* __restrict__ Wa, const float* __restrict__ ba,
    const float* __restrict__ Wao, const float* __restrict__ bao,
    __hip_bfloat16* __restrict__ arc_f, __hip_bfloat16* __restrict__ arc_b,
    ull* __restrict__ hpay, ull* __restrict__ zpay, int* __restrict__ claims) {

    // ---- XCD-affine slot claim ----
    __shared__ int s_slot;
    if (threadIdx.x == 0) {
        unsigned xcc = (unsigned)__builtin_amdgcn_s_getreg((31 << 11) | (0 << 6) | 20) & 15u;
        int slot = -1;
        if (xcc <= 1) {
            int c = atomicAdd(&claims[xcc], 1);
            if (c < 32) slot = (int)xcc * 32 + c;
        } else {
            for (int sl = 0; sl < 64; sl++) __builtin_amdgcn_s_sleep(64);
            for (int dd = 0; dd < 2 && slot < 0; dd++) {
                if (__hip_atomic_load(&claims[dd], __ATOMIC_RELAXED,
                                      __HIP_MEMORY_SCOPE_AGENT) < 32) {
                    int c = atomicAdd(&claims[dd], 1);
                    if (c < 32) slot = dd * 32 + c;
                }
            }
        }
        s_slot = slot;
    }
    __syncthreads();
    const int slot = s_slot;
    if (slot < 0) return;
    const int dir = slot >> 5;
    const int b   = slot & 31;

    const float* __restrict__ Whh = dir ? Whh_b : Whh_f;
    const float* __restrict__ Wih = dir ? Wih_b : Wih_f;
    const float* __restrict__ bia = dir ? b_b  : b_f;
    __hip_bfloat16* __restrict__ arc = dir ? arc_b : arc_f;
    const int tid = threadIdx.x;

    // matvec roles: 64 gate rows x 4-way K split
    const int jl = tid >> 2, ks = tid & 3;
    const int Jg = (jl >> 4) * kH + b * 16 + (jl & 15);
    // gate / xproj / z roles: wave = arc, lane = gate row (or attention unit)
    const int d_g = tid >> 6, jl2 = tid & 63;
    const int Jg2 = (jl2 >> 4) * kH + b * 16 + (jl2 & 15);
    const int a_id = jl2;

    float w[128];
    {
        const float* wr = Whh + (size_t)Jg * kH + ks * 128;
        #pragma unroll
        for (int kk = 0; kk < 128; kk++) w[kk] = wr[kk];
    }
    float wih[64];
    {
        const float* wr = Wih + (size_t)Jg2 * kF + d_g * 64;
        #pragma unroll
        for (int kk = 0; kk < 64; kk++) wih[kk] = wr[kk];
    }
    const float biasR = bia[Jg2];
    const float baR   = ba[a_id];
    const float WaoR  = Wao[a_id];
    const float baoR  = bao[0];
    const float wax0  = Wa[(size_t)a_id * 515 + 512];
    const float wax1  = Wa[(size_t)a_id * 515 + 513];
    const float wax2  = Wa[(size_t)a_id * 515 + 514];

    // hprev padded: 4 chunks of 132 floats (banks offset 4 per chunk -> no conflict)
    __shared__ __align__(16) float hprev_p[4 * 132];
    __shared__ float Mh[4][64];
    __shared__ float cring[4][16];
    __shared__ float harcl[4][16];
    __shared__ float carcl[4][16];
    __shared__ float logit_l[4];
    __shared__ float WaS[64][17];
    __shared__ float xpl[2][4][64];      // parity-buffered gate-x projection
    __shared__ __align__(16) float x_s[4][256];
    __shared__ float xpart[4][4][64];

    for (int l2 = tid; l2 < 4 * 132; l2 += 256) hprev_p[l2] = 0.f;
    Mh[tid >> 6][tid & 63] = 0.f;
    if (tid < 64) cring[tid >> 4][tid & 15] = 0.f;
    for (int l2 = tid; l2 < 1024; l2 += 256)
        WaS[l2 >> 4][l2 & 15] = Wa[(size_t)(l2 >> 4) * 515 + b * 16 + (l2 & 15)];
    __syncthreads();

// issue the edge-row load for node nn (block-uniform)
#define XLOAD(nn, XV) do {                                                    \
        int row_;                                                             \
        if (dir == 0) row_ = (nn) * 4 + d_g;                                  \
        else { row_ = ((nn) + 1 + d_g) * 4 + d_g;                             \
               if (row_ > kE - 1) row_ = kE - 1; }                            \
        XV = *(const float4*)(edges + (size_t)row_ * kF + 4 * jl2);           \
    } while (0)

// finish xproj from a prefetched edge vector into xpl[BUF]; returns zx
#define XFIN(XV, BUF, ZXOUT) do {                                             \
        *(float4*)(&x_s[d_g][4 * jl2]) = XV;                                  \
        __syncthreads();                                                      \
        float p0_ = 0.f, p1_ = 0.f, p2_ = 0.f, p3_ = 0.f;                     \
        _Pragma("unroll")                                                     \
        for (int k4_ = 0; k4_ < 16; k4_++) {                                  \
            float4 a0_ = *(const float4*)&x_s[0][d_g * 64 + k4_ * 4];         \
            float4 a1_ = *(const float4*)&x_s[1][d_g * 64 + k4_ * 4];         \
            float4 a2_ = *(const float4*)&x_s[2][d_g * 64 + k4_ * 4];         \
            float4 a3_ = *(const float4*)&x_s[3][d_g * 64 + k4_ * 4];         \
            float w0_ = wih[k4_*4], w1_ = wih[k4_*4+1];                       \
            float w2_ = wih[k4_*4+2], w3_ = wih[k4_*4+3];                     \
            p0_ += w0_*a0_.x + w1_*a0_.y + w2_*a0_.z + w3_*a0_.w;             \
            p1_ += w0_*a1_.x + w1_*a1_.y + w2_*a1_.z + w3_*a1_.w;             \
            p2_ += w0_*a2_.x + w1_*a2_.y + w2_*a2_.z + w3_*a2_.w;             \
            p3_ += w0_*a3_.x + w1_*a3_.y + w2_*a3_.z + w3_*a3_.w;             \
        }                                                                     \
        xpart[d_g][0][jl2] = p0_; xpart[d_g][1][jl2] = p1_;                   \
        xpart[d_g][2][jl2] = p2_; xpart[d_g][3][jl2] = p3_;                   \
        __syncthreads();                                                      \
        xpl[BUF][d_g][jl2] = biasR + xpart[0][d_g][jl2] + xpart[1][d_g][jl2]  \
                                   + xpart[2][d_g][jl2] + xpart[3][d_g][jl2]; \
        ZXOUT = baR + wax0 * x_s[d_g][0] + wax1 * x_s[d_g][1]                 \
                    + wax2 * x_s[d_g][2];                                     \
    } while (0)

    const int i0 = dir ? kN - 1 : 0;
    float zxv, zx_n;
    {
        float4 xv0;
        XLOAD(i0, xv0);
        XFIN(xv0, 0, zxv);
    }
    __syncthreads();   // xpl[0] visible before t=0 cell

    for (int t = 0; t < kN; t++) {
        const int i = dir ? kN - 1 - t : t;
        const unsigned stamp = (unsigned)(t + 1);
        const int par = t & 1;

        // ---- prefetch next step's edge row (latency overlaps phase A) ----
        float4 xv_n;
        {
            const int nn = (t + 1 < kN) ? (dir ? i - 1 : i + 1) : i;
            XLOAD(nn, xv_n);
        }

        // ---- A: M[iprev] = hprev . Whh^T (own 64 rows) ----
        float acc = 0.f;
        {
            const float* hp = &hprev_p[ks * 132];
            #pragma unroll
            for (int kk = 0; kk < 128; kk += 4) {
                float4 hv = *(const float4*)(hp + kk);
                acc += w[kk] * hv.x + w[kk+1] * hv.y + w[kk+2] * hv.z + w[kk+3] * hv.w;
            }
        }
        acc += __shfl_xor(acc, 1);
        acc += __shfl_xor(acc, 2);
        const int iprev = dir ? i + 1 : i - 1;
        if (ks == 0) Mh[iprev & 3][jl] = acc;
        __syncthreads();   // B1: Mh ready

        // ---- B: fused per-wave cell (wave = arc, lanes<16) + publish h ----
        const int pp = dir ? i + 1 + d_g : i - 1 - d_g;
        const bool v3 = dir ? (pp < kN) : (pp >= 0);
        if (jl2 < 16) {
            const int s3 = jl2;
            float gi = xpl[par][d_g][s3]      + Mh[pp & 3][s3];
            float gf = xpl[par][d_g][16 + s3] + Mh[pp & 3][16 + s3];
            float gg = xpl[par][d_g][32 + s3] + Mh[pp & 3][32 + s3];
            float go = xpl[par][d_g][48 + s3] + Mh[pp & 3][48 + s3];
            float cp = cring[pp & 3][s3];
            float c = sigm(gf) * cp + sigm(gi) * tanhf(gg);
            float h = sigm(go) * tanhf(c);
            float hm = v3 ? h : 0.f, cm = v3 ? c : 0.f;
            harcl[d_g][s3] = hm; carcl[d_g][s3] = cm;
            st_pair(hpay + (((dir * 2 + par) * 4 + d_g) << 9) + b * 16 + s3, hm, stamp);
            arc[((size_t)i * 4 + d_g) * kH + b * 16 + s3] = __float2bfloat16(hm);
        }
        // z partial over own 16 h-dims (intra-wave harcl dep -> no barrier)
        {
            float zp = 0.f;
            #pragma unroll
            for (int ss = 0; ss < 16; ss++) zp += WaS[a_id][ss] * harcl[d_g][ss];
            st_pair(zpay + (((dir * 2 + par) * 32 + b) << 8) + tid, zp, stamp);
        }

        // ---- C: next step's input projection (overlaps publish visibility;
        //         its 2 barriers order harcl/carcl for the combine) ----
        float xp_dummy; (void)xp_dummy;
        XFIN(xv_n, par ^ 1, zx_n);

        // ---- E: batched stamped loads (z + h) ----
        const ull* zb = zpay + (((size_t)(dir * 2 + par) * 32) << 8) + tid;
        ull zv_[32];
        #pragma unroll
        for (int bb = 0; bb < 32; bb++) zv_[bb] = ld_raw(zb + ((size_t)bb << 8));
        const ull* hb = hpay + (((size_t)(dir * 2 + par) * 4) << 9);
        ull hv_[8];
        #pragma unroll
        for (int dd = 0; dd < 4; dd++) {
            hv_[2*dd]   = ld_raw(hb + (dd << 9) + 2 * tid);
            hv_[2*dd+1] = ld_raw(hb + (dd << 9) + 2 * tid + 1);
        }

        // resolve z: batched sweeps with backoff
        for (;;) {
            bool ok = true;
            #pragma unroll
            for (int bb = 0; bb < 32; bb++)
                ok &= ((unsigned)(zv_[bb] >> 32) == stamp);
            if (ok) break;
            __builtin_amdgcn_s_sleep(2);
            #pragma unroll
            for (int bb = 0; bb < 32; bb++)
                if ((unsigned)(zv_[bb] >> 32) != stamp)
                    zv_[bb] = ld_raw(zb + ((size_t)bb << 8));
        }
        float zsum = 0.f;
        #pragma unroll
        for (int bb = 0; bb < 32; bb++) zsum += __uint_as_float((unsigned)zv_[bb]);

        // resolve h: batched sweeps with backoff
        for (;;) {
            bool ok = true;
            #pragma unroll
            for (int q = 0; q < 8; q++)
                ok &= ((unsigned)(hv_[q] >> 32) == stamp);
            if (ok) break;
            __builtin_amdgcn_s_sleep(2);
            #pragma unroll
            for (int dd = 0; dd < 4; dd++) {
                if ((unsigned)(hv_[2*dd]   >> 32) != stamp) hv_[2*dd]   = ld_raw(hb + (dd << 9) + 2 * tid);
                if ((unsigned)(hv_[2*dd+1] >> 32) != stamp) hv_[2*dd+1] = ld_raw(hb + (dd << 9) + 2 * tid + 1);
            }
        }

        float zv = fmaxf(zsum + zxv, 0.f);
        float lv = WaoR * zv;
        #pragma unroll
        for (int o2 = 1; o2 < 64; o2 <<= 1) lv += __shfl_xor(lv, o2);
        if (a_id == 0) {
            logit_l[d_g] = v3 ? tanhf(lv + baoR) : -1e9f;
        }
        __syncthreads();   // B4: logits ready

        float l0 = logit_l[0], l1 = logit_l[1], l2 = logit_l[2], l3 = logit_l[3];
        float mx = fmaxf(fmaxf(l0, l1), fmaxf(l2, l3));
        float e0 = __expf(l0 - mx), e1 = __expf(l1 - mx);
        float e2 = __expf(l2 - mx), e3 = __expf(l3 - mx);
        float inv = 1.f / (e0 + e1 + e2 + e3);
        float wg[4] = { e0 * inv, e1 * inv, e2 * inv, e3 * inv };

        float hn0 = 0.f, hn1 = 0.f;
        #pragma unroll
        for (int dd = 0; dd < 4; dd++) {
            hn0 += wg[dd] * __uint_as_float((unsigned)hv_[2*dd]);
            hn1 += wg[dd] * __uint_as_float((unsigned)hv_[2*dd+1]);
        }
        {
            const int g = 2 * tid;
            const int ch = g >> 7, wi = g & 127;
            hprev_p[ch * 132 + wi]     = hn0;
            hprev_p[ch * 132 + wi + 1] = hn1;
        }
        if (tid < 16) {
            float cn = wg[0] * carcl[0][tid] + wg[1] * carcl[1][tid]
                     + wg[2] * carcl[2][tid] + wg[3] * carcl[3][tid];
            cring[i & 3][tid] = cn;
        }
        __syncthreads();   // B5: hprev/cring ready for next step

        zxv = zx_n;
    }
#undef XLOAD
#undef XFIN
}

// ---------------------------------------------------------------------------
// decoder: out[e] += sum_l Wdo[l] * relu(bd[l] + sum_k Wd[l,k] feat[e,k])
// ---------------------------------------------------------------------------
__global__ __launch_bounds__(256) void k_dec(
    const __hip_bfloat16* __restrict__ arc_f, const __hip_bfloat16* __restrict__ arc_b,
    const float* __restrict__ Wd, const float* __restrict__ bd,
    const float* __restrict__ Wdo, float* __restrict__ out) {
    const int e0 = blockIdx.x * 128;
    const int l0 = blockIdx.y * 128;
    __shared__ __align__(16) float As[8][128];
    __shared__ __align__(16) float Bs[8][128];
    const int tid = threadIdx.x;
    const int tx = tid & 15, ty = tid >> 4;
    const int lr = tid & 127, kq = tid >> 7;

    const int e = e0 + lr;
    const int j = e >> 2, d = e & 3;
    const int jb = j - 1 - d;
    const __hip_bfloat16* frow  = arc_f + (size_t)e * kH;
    const __hip_bfloat16* brow2 = (jb >= 0) ? (arc_b + ((size_t)jb * 4 + d) * kH) : nullptr;
    const float* wrow = Wd + (size_t)(l0 + lr) * (2 * kH);

    float acc[8][8] = {};
    for (int k0 = 0; k0 < 2 * kH; k0 += 8) {
        const int kk = k0 + kq * 4;
        float4 av4;
        if (kk < kH) av4 = ld_bf4(frow + kk);
        else if (brow2) av4 = ld_bf4(brow2 + (kk - kH));
        else av4 = make_float4(0.f, 0.f, 0.f, 0.f);
        float4 bv4 = *(const float4*)(wrow + kk);
        __syncthreads();
        As[kq*4+0][lr] = av4.x; As[kq*4+1][lr] = av4.y;
        As[kq*4+2][lr] = av4.z; As[kq*4+3][lr] = av4.w;
        Bs[kq*4+0][lr] = bv4.x; Bs[kq*4+1][lr] = bv4.y;
        Bs[kq*4+2][lr] = bv4.z; Bs[kq*4+3][lr] = bv4.w;
        __syncthreads();
        #pragma unroll
        for (int kt = 0; kt < 8; kt++) {
            __align__(16) float a0[8], b0[8];
            *(float4*)&a0[0] = *(const float4*)&As[kt][ty*8];
            *(float4*)&a0[4] = *(const float4*)&As[kt][ty*8+4];
            *(float4*)&b0[0] = *(const float4*)&Bs[kt][tx*8];
            *(float4*)&b0[4] = *(const float4*)&Bs[kt][tx*8+4];
            #pragma unroll
            for (int mi = 0; mi < 8; mi++)
                #pragma unroll
                for (int ni = 0; ni < 8; ni++)
                    acc[mi][ni] += a0[mi] * b0[ni];
        }
    }
    #pragma unroll
    for (int mi = 0; mi < 8; mi++) {
        float sacc = 0.f;
        #pragma unroll
        for (int ni = 0; ni < 8; ni++) {
            int l = l0 + tx * 8 + ni;
            sacc += Wdo[l] * fmaxf(acc[mi][ni] + bd[l], 0.f);
        }
        sacc += __shfl_xor(sacc, 1);
        sacc += __shfl_xor(sacc, 2);
        sacc += __shfl_xor(sacc, 4);
        sacc += __shfl_xor(sacc, 8);
        if (tx == 0) atomicAdd(out + e0 + ty * 8 + mi, sacc);
    }
}

// ---------------------------------------------------------------------------
extern "C" void kernel_launch(void* const* d_in, const int* in_sizes, int n_in,
                              void* d_out, int out_size, void* d_ws, size_t ws_size,
                              hipStream_t stream) {
    const float* edges = (const float*)d_in[0];
    const float* Wih_f = (const float*)d_in[1];
    const float* Whh_f = (const float*)d_in[2];
    const float* b_f   = (const float*)d_in[3];
    const float* Wih_b = (const float*)d_in[4];
    const float* Whh_b = (const float*)d_in[5];
    const float* b_b   = (const float*)d_in[6];
    const float* Wa    = (const float*)d_in[7];
    const float* ba    = (const float*)d_in[8];
    const float* Wao   = (const float*)d_in[9];
    const float* bao   = (const float*)d_in[10];
    const float* Wd    = (const float*)d_in[11];
    const float* bd    = (const float*)d_in[12];
    const float* Wdo   = (const float*)d_in[13];
    const float* bdo   = (const float*)d_in[14];
    float* out = (float*)d_out;

    char* ws = (char*)d_ws;
    size_t off = 0;
    __hip_bfloat16* arc_f = (__hip_bfloat16*)(ws + off); off += (size_t)kE * kH * 2;  // 32 MB
    __hip_bfloat16* arc_b = (__hip_bfloat16*)(ws + off); off += (size_t)kE * kH * 2;  // 32 MB
    ull* hpay = (ull*)(ws + off); off += (size_t)2 * 2 * 4 * kH * 8;                  // 64 KB
    ull* zpay = (ull*)(ws + off); off += (size_t)2 * 2 * 32 * 256 * 8;                // 256 KB
    int* claims = (int*)(ws + off); off += 64;

    if (ws_size < off) {
        hipLaunchKernelGGL(k_zero, dim3((kE + 255) / 256), dim3(256), 0, stream, out);
        return;
    }

    hipLaunchKernelGGL(k_init, dim3(128), dim3(256), 0, stream,
                       out, bdo, hpay, zpay, claims);
    hipLaunchKernelGGL(k_recur, dim3(512), dim3(256), 0, stream,
                       edges, Wih_f, Whh_f, b_f, Wih_b, Whh_b, b_b,
                       Wa, ba, Wao, bao, arc_f, arc_b, hpay, zpay, claims);
    hipLaunchKernelGGL(k_dec, dim3(kE / 128, kL / 128), dim3(256), 0, stream,
                       arc_f, arc_b, Wd, bd, Wdo, out);
}